// Round 14
// baseline (349.721 us; speedup 1.0000x reference)
//
#include <hip/hip_runtime.h>
#include <hip/hip_bf16.h>
#include <stdint.h>

typedef __attribute__((ext_vector_type(8))) short short8;
typedef __attribute__((ext_vector_type(4))) float f32x4;

// Problem constants
#define BATCH 4
#define SEQ   2048
#define EMB   1024
#define HEADS 16
#define DHEAD 64
#define MROWS (BATCH * SEQ)   // 8192
#define NW    (EMB * EMB)     // 1048576

// exp(s/8) == exp2(s * 0.125*log2(e)); fold into Q at bf16-pack time
#define QSCALE 0.18033688011112042f

__device__ inline unsigned short f2bf(float f) {
    unsigned int u = __float_as_uint(f);
    unsigned int r = (u + 0x7fffu + ((u >> 16) & 1u)) >> 16;
    return (unsigned short)r;
}

__device__ __forceinline__ void gl_lds16(const short* g, short* l) {
    __builtin_amdgcn_global_load_lds(
        (const __attribute__((address_space(1))) void*)g,
        (__attribute__((address_space(3))) void*)l, 16, 0, 0);
}

template <int N>
__device__ __forceinline__ void waitvm() {
    asm volatile("s_waitcnt vmcnt(%0)" :: "n"(N) : "memory");
}

// ------- fused pack: x -> bf16 + f32 passthrough, and Wq|Wk|Wv -> bf16 ---
__global__ __launch_bounds__(256) void pack_all(const float* __restrict__ x,
                                                const float* __restrict__ wq,
                                                const float* __restrict__ wk,
                                                const float* __restrict__ wv,
                                                unsigned short* __restrict__ xb,
                                                unsigned short* __restrict__ wb,
                                                float* __restrict__ pass) {
    const int i = (blockIdx.x * 256 + threadIdx.x) * 8;
    const float* src;
    unsigned short* dst;
    bool isx = i < MROWS * EMB;
    if (isx) {
        src = x + i;
        dst = xb + i;
    } else {
        const int j = i - MROWS * EMB;
        src = (j < NW) ? wq + j : (j < 2 * NW) ? wk + (j - NW) : wv + (j - 2 * NW);
        dst = wb + j;
    }
    const float4* s = reinterpret_cast<const float4*>(src);
    float4 f0 = s[0];
    float4 f1 = s[1];
    union { unsigned short u[8]; short8 v; } o;
    o.u[0] = f2bf(f0.x); o.u[1] = f2bf(f0.y); o.u[2] = f2bf(f0.z); o.u[3] = f2bf(f0.w);
    o.u[4] = f2bf(f1.x); o.u[5] = f2bf(f1.y); o.u[6] = f2bf(f1.z); o.u[7] = f2bf(f1.w);
    *reinterpret_cast<short8*>(dst) = o.v;
    if (isx) {
        float4* p = reinterpret_cast<float4*>(pass + i);
        p[0] = f0;
        p[1] = f1;
    }
}

// ---------------- 8-wave 256-wide pipelined GEMM ------------------------
// C[m,n] = sum_k A[m,k] * B[n,k]  (NT, bf16 in), K = 1024, BK = 32.
// 3 LDS buffers, depth-2 prefetch via global_load_lds, one raw s_barrier +
// counted vmcnt per K-tile (T3+T4), setprio on MFMA (T5), granule swizzle
// via pre-swizzled global source (T2, rule #21).
// MODE 0: BN=256, cols span [Wq|Wk]; bf16 head-major out, Q scaled QSCALE.
// MODE 1: BN=128, f32 out scaled by num/(pp0+pp1) (softmax-diag combine).
template <int MODE>
__global__ __launch_bounds__(512, 2) void gemm8(const short* __restrict__ A,
                                                const short* __restrict__ Bm,
                                                unsigned short* __restrict__ Cb,
                                                float* __restrict__ out,
                                                const float* __restrict__ num,
                                                const float* __restrict__ pp) {
    constexpr int K = EMB;
    constexpr int NT = K / 32;                 // 32 K-tiles
    constexpr int BN = (MODE == 0) ? 256 : 128;
    constexpr int NF = BN / 64;                // N-frags per wave: 4 or 2
    constexpr int BUFSTRIDE = 8192 + BN * 32;  // shorts per buffer
    constexpr int VW = 2 + BN / 128;           // vmem ops per wave per tile: 4 or 3

    __shared__ short Ks[3 * BUFSTRIDE];        // 96 KB (MODE0) / 72 KB (MODE1)

    const int t = threadIdx.x;
    const int lane = t & 63;
    const int w = t >> 6;            // 0..7
    const int wr = w >> 2;           // 0..1   M half
    const int wc = w & 3;            // 0..3   N quarter
    const int rl = lane & 15;
    const int pg = (lane >> 4) ^ (lane & 3);   // swizzled read granule
    const int m0 = blockIdx.x * 256;
    const int n0 = blockIdx.y * BN;

    const int sr = t >> 2;                     // 0..127
    const int sg = (t & 3) ^ (sr & 3);
    const int soff = sr * K + sg * 8;
    const short* gA0 = A + (size_t)(m0)*K + soff;
    const short* gA1 = A + (size_t)(m0 + 128) * K + soff;
    const short* gB0 = Bm + (size_t)(n0)*K + soff;
    const short* gB1 = Bm + (size_t)(n0 + 128) * K + soff;  // MODE0 only
    short* ldsw = Ks + w * 512;                // wave-uniform stage base

#define STAGE8(kk, bb)                                               \
    {                                                                \
        const int _k = (kk)*32;                                      \
        short* _l = ldsw + (bb)*BUFSTRIDE;                           \
        gl_lds16(gA0 + _k, _l);                                      \
        gl_lds16(gA1 + _k, _l + 4096);                               \
        gl_lds16(gB0 + _k, _l + 8192);                               \
        if (MODE == 0) gl_lds16(gB1 + _k, _l + 12288);               \
    }

    f32x4 acc[8][NF] = {};

    // prologue: tiles 0,1 -> bufs 0,1
    STAGE8(0, 0);
    STAGE8(1, 1);
    waitvm<VW>();                    // tile 0 landed
    __builtin_amdgcn_s_barrier();

    int cur = 0;
    for (int kt = 0; kt < NT; ++kt) {
        const int pf = kt + 2;
        if (pf < NT) {
            int nb = cur + 2; if (nb >= 3) nb -= 3;
            STAGE8(pf, nb);
        }

        const short* bufp = Ks + cur * BUFSTRIDE;
        short8 av[8], bv[NF];
#pragma unroll
        for (int i = 0; i < 8; i++)
            av[i] = *(const short8*)&bufp[wr * 4096 + i * 512 + rl * 32 + pg * 8];
#pragma unroll
        for (int j = 0; j < NF; j++) {
            const int brow = (MODE == 0) ? ((wc & 1) * 64 + j * 16 + rl)
                                         : (wc * 32 + j * 16 + rl);
            const int bh = (MODE == 0) ? (wc >> 1) : 0;
            bv[j] = *(const short8*)&bufp[8192 + bh * 4096 + brow * 32 + pg * 8];
        }

        __builtin_amdgcn_s_setprio(1);
#pragma unroll
        for (int i = 0; i < 8; i++)
#pragma unroll
            for (int j = 0; j < NF; j++)
                acc[i][j] = __builtin_amdgcn_mfma_f32_16x16x32_bf16(av[i], bv[j], acc[i][j], 0, 0, 0);
        __builtin_amdgcn_s_setprio(0);

        if (kt < NT - 2) waitvm<VW>();   // next tile landed; prefetch stays in flight
        else             waitvm<0>();
        __builtin_amdgcn_s_barrier();

        cur += 1; if (cur == 3) cur = 0;
    }
#undef STAGE8

    // epilogue: C layout col = lane&15, row = 4*(lane>>4)+r
    const int gr_base = m0 + wr * 128 + (lane >> 4) * 4;
    const int gc_base = n0 + wc * (BN / 4) + rl;
#pragma unroll
    for (int i = 0; i < 8; i++) {
#pragma unroll
        for (int j = 0; j < NF; j++) {
            const int col = gc_base + j * 16;
#pragma unroll
            for (int r = 0; r < 4; r++) {
                const int grow = gr_base + i * 16 + r;
                const int bb = grow >> 11;
                const int nn = grow & 2047;
                if (MODE == 0) {
                    const int sel = col >> 10;       // 0 = Q, 1 = K
                    const int cc = col & 1023;
                    const int hh = cc >> 6;
                    const int dd = cc & 63;
                    const float sc = sel ? 1.0f : QSCALE;
                    Cb[(((size_t)((sel << 6) + (bb << 4) + hh) * SEQ + nn) << 6) + dd] =
                        f2bf(acc[i][j][r] * sc);
                } else {
                    const int hh = col >> 6;
                    const int idx = ((bb << 4) + hh) * SEQ + nn;
                    const float d = num[idx] / (pp[idx] + pp[idx + 64 * SEQ]);
                    out[(size_t)grow * EMB + col] = acc[i][j][r] * d;
                }
            }
        }
    }
}

// ---------------- diag kernel v13: 64 q-rows/wave + k-split x2 -----------
// Qh/Kh head-major [64][2048][64] bf16 (Q pre-scaled by QSCALE).
// Block = (bh, qt: 512 q-rows, ks: k half). 512 thr = 8 waves x 64 q-rows
// (4 tiles) -> one LDS read pair feeds 8 MFMAs (LDS reads/score halved).
// Grid 512, 2 blocks/CU, 16 waves/CU. v7 staging: global_load_lds with
// pre-swizzled global src (rule #21), 3 LDS bufs, depth-2 prefetch,
// counted vmcnt, ONE barrier per tile, NO setprio (r13: caused spills).
// Writes partials pp[ks][bh][q]; ks==0 blocks also write num[bh][q].
__global__ __launch_bounds__(512, 4) void diag_kernel(const short* __restrict__ Qh,
                                                      const short* __restrict__ Kh,
                                                      float* __restrict__ num,
                                                      float* __restrict__ pp) {
    const int n = blockIdx.x;
    const int bh = (n & 7) | ((n >> 6) << 3);   // 0..63 (XCD-pinned both maps)
    const int qt = (n >> 3) & 3;                // 4 q-tiles of 512 rows
    const int ks = (n >> 5) & 1;                // k half (1024 rows)
    __shared__ short Ksd[3 * 8192];             // 3 bufs x 128 rows x 64

    const int t = threadIdx.x;
    const int lane = t & 63;
    const int w = t >> 6;               // 0..7
    const int rl = lane & 15;
    const int g = lane >> 4;            // 0..3
    const int kq = g * 8;

    const short* Kbh = Kh + (size_t)bh * SEQ * DHEAD;
    const short* Qbh = Qh + (size_t)bh * SEQ * DHEAD;

    // Q fragments: 4 tiles of 16 rows (64 q-rows per wave)
    const int qbase = qt * 512 + w * 64;
    short8 a0[4], a1[4];
#pragma unroll
    for (int i = 0; i < 4; i++) {
        const int qrow = qbase + i * 16 + rl;
        a0[i] = *(const short8*)(Qbh + qrow * DHEAD + kq);
        a1[i] = *(const short8*)(Qbh + qrow * DHEAD + kq + 32);
    }

    const int rr = rl - g * 4;          // valid lane iff 0 <= rr < 4

    // diag numerator pre-pass: ks==0 blocks only (global K reads, cheap)
    if (ks == 0) {
        float sdiag[4];
#pragma unroll
        for (int i = 0; i < 4; i++) {
            const int krow = qbase + i * 16 + rl;
            const short8 b0d = *(const short8*)(Kbh + krow * DHEAD + kq);
            const short8 b1d = *(const short8*)(Kbh + krow * DHEAD + kq + 32);
            f32x4 cd = {};
            cd = __builtin_amdgcn_mfma_f32_16x16x32_bf16(a0[i], b0d, cd, 0, 0, 0);
            cd = __builtin_amdgcn_mfma_f32_16x16x32_bf16(a1[i], b1d, cd, 0, 0, 0);
            sdiag[i] = (rr >= 0 && rr < 4) ? cd[rr] : 0.f;
        }
        if (rr >= 0 && rr < 4) {
#pragma unroll
            for (int i = 0; i < 4; i++)
                num[bh * SEQ + qbase + i * 16 + rl] =
                    __builtin_amdgcn_exp2f(sdiag[i]);
        }
    }

    // staging: thread t sources granule (row t>>3, block (t&7)^(row&7));
    // LDS dest linear (granule t) => LDS holds logical block b at b^(row&7).
    const int sr = t >> 3;              // 0..63
    const int sb = ((t & 7) ^ (sr & 7)) * 8;
    const short* gK0 = Kbh + (size_t)ks * 1024 * DHEAD + sr * DHEAD + sb;
    const short* gK1 = gK0 + 64 * DHEAD;
    short* ldsw = Ksd + w * 512;        // wave-uniform stage base

#define DSTAGE(kk, bb)                                        \
    {                                                         \
        gl_lds16(gK0 + (kk)*8192, ldsw + (bb)*8192);          \
        gl_lds16(gK1 + (kk)*8192, ldsw + (bb)*8192 + 4096);   \
    }

    // swizzled read blocks (row&7 == lane&7 since rows step by 16)
    const int blk0 = (g ^ (lane & 7)) * 8;
    const int blk1 = ((g + 4) ^ (lane & 7)) * 8;

    float ssum[4][4] = {};

    DSTAGE(0, 0);
    DSTAGE(1, 1);
    waitvm<2>();                        // tile 0 landed
    __builtin_amdgcn_s_barrier();

#define QKMFMA(sub, c)                                                          \
    {                                                                           \
        const short* _r = bufp + ((sub)*16 + rl) * 64;                          \
        const short8 _b0 = *(const short8*)(_r + blk0);                         \
        const short8 _b1 = *(const short8*)(_r + blk1);                         \
        _Pragma("unroll") for (int i = 0; i < 4; i++) {                         \
            c[i] = __builtin_amdgcn_mfma_f32_16x16x32_bf16(a0[i], _b0, f32x4{}, 0, 0, 0); \
            c[i] = __builtin_amdgcn_mfma_f32_16x16x32_bf16(a1[i], _b1, c[i], 0, 0, 0);    \
        }                                                                       \
    }
#define EXPACC(c)                                         \
    {                                                     \
        _Pragma("unroll") for (int i = 0; i < 4; i++)     \
        _Pragma("unroll") for (int r = 0; r < 4; ++r)     \
            ssum[i][r] += __builtin_amdgcn_exp2f(c[i][r]); \
    }

    int cur = 0;
    for (int kt = 0; kt < 8; ++kt) {
        if (kt + 2 < 8) {
            int nb = cur + 2; if (nb >= 3) nb -= 3;
            DSTAGE(kt + 2, nb);
        }
        const short* bufp = Ksd + cur * 8192;

        f32x4 cE[4], cO[4];
        QKMFMA(0, cE);
        QKMFMA(1, cO);
        EXPACC(cE);
        QKMFMA(2, cE);
        EXPACC(cO);
        QKMFMA(3, cO);
        EXPACC(cE);
        QKMFMA(4, cE);
        EXPACC(cO);
        QKMFMA(5, cO);
        EXPACC(cE);
        QKMFMA(6, cE);
        EXPACC(cO);
        QKMFMA(7, cO);
        EXPACC(cE);
        EXPACC(cO);

        if (kt < 7) {
            if (kt < 6) waitvm<2>();
            else        waitvm<0>();
            __builtin_amdgcn_s_barrier();
        }
        cur += 1; if (cur == 3) cur = 0;
    }
#undef DSTAGE
#undef QKMFMA
#undef EXPACC

    // reduce partial sums across the 16-lane column groups
#pragma unroll
    for (int i = 0; i < 4; i++)
#pragma unroll
        for (int r = 0; r < 4; r++) {
            float v = ssum[i][r];
            v += __shfl_xor(v, 1);
            v += __shfl_xor(v, 2);
            v += __shfl_xor(v, 4);
            v += __shfl_xor(v, 8);
            ssum[i][r] = v;
        }

    if (rr >= 0 && rr < 4) {
#pragma unroll
        for (int i = 0; i < 4; i++)
            pp[(ks * 64 + bh) * SEQ + qbase + i * 16 + rl] = ssum[i][rr];
    }
}

extern "C" void kernel_launch(void* const* d_in, const int* in_sizes, int n_in,
                              void* d_out, int out_size, void* d_ws, size_t ws_size,
                              hipStream_t stream) {
    const float* x  = (const float*)d_in[0];
    const float* Wq = (const float*)d_in[1];
    const float* Wk = (const float*)d_in[2];
    const float* Wv = (const float*)d_in[3];
    float* out = (float*)d_out;
    char* ws = (char*)d_ws;

    const size_t xb_off  = 0;
    const size_t wq_off  = xb_off + (size_t)MROWS * EMB * 2;
    const size_t wk_off  = wq_off + (size_t)NW * 2;          // contiguous after wq
    const size_t wv_off  = wk_off + (size_t)NW * 2;
    const size_t q_off   = wv_off + (size_t)NW * 2;
    const size_t k_off   = q_off + (size_t)MROWS * EMB * 2;  // contiguous after q
    const size_t num_off = k_off + (size_t)MROWS * EMB * 2;
    const size_t pp_off  = num_off + (size_t)64 * SEQ * 4;

    short* xb  = (short*)(ws + xb_off);
    short* wqb = (short*)(ws + wq_off);
    short* wvb = (short*)(ws + wv_off);
    short* Qh  = (short*)(ws + q_off);
    short* Kh  = (short*)(ws + k_off);
    float* num = (float*)(ws + num_off);
    float* pp  = (float*)(ws + pp_off);

    const int npack = (MROWS * EMB + 3 * NW) / 2048;   // 5632 blocks

    pack_all<<<npack, 256, 0, stream>>>(x, Wq, Wk, Wv,
                                        (unsigned short*)xb, (unsigned short*)wqb,
                                        out + (size_t)MROWS * EMB);

    // fused Q+K projection: B = [Wq | Wk] (contiguous), N = 2048
    gemm8<0><<<dim3(MROWS / 256, 2048 / 256), 512, 0, stream>>>(
        xb, wqb, (unsigned short*)Qh, nullptr, nullptr, nullptr);

    diag_kernel<<<512, 512, 0, stream>>>(Qh, Kh, num, pp);

    gemm8<1><<<dim3(MROWS / 256, EMB / 128), 512, 0, stream>>>(
        xb, wvb, nullptr, out, num, pp);
}

// Round 15
// 133.455 us; speedup vs baseline: 2.6205x; 2.6205x over previous
//
#include <hip/hip_runtime.h>
#include <hip/hip_bf16.h>
#include <stdint.h>

typedef __attribute__((ext_vector_type(8))) short short8;
typedef __attribute__((ext_vector_type(4))) float f32x4;

// Problem constants
#define BATCH 4
#define SEQ   2048
#define EMB   1024
#define HEADS 16
#define DHEAD 64
#define MROWS (BATCH * SEQ)   // 8192
#define NW    (EMB * EMB)     // 1048576

// exp(s/8) == exp2(s * 0.125*log2(e)); fold into Q at bf16-pack time
#define QSCALE 0.18033688011112042f

__device__ inline unsigned short f2bf(float f) {
    unsigned int u = __float_as_uint(f);
    unsigned int r = (u + 0x7fffu + ((u >> 16) & 1u)) >> 16;
    return (unsigned short)r;
}

__device__ __forceinline__ void gl_lds16(const short* g, short* l) {
    __builtin_amdgcn_global_load_lds(
        (const __attribute__((address_space(1))) void*)g,
        (__attribute__((address_space(3))) void*)l, 16, 0, 0);
}

template <int N>
__device__ __forceinline__ void waitvm() {
    asm volatile("s_waitcnt vmcnt(%0)" :: "n"(N) : "memory");
}

// ------- fused pack: x -> bf16 + f32 passthrough, and Wq|Wk|Wv -> bf16 ---
__global__ __launch_bounds__(256) void pack_all(const float* __restrict__ x,
                                                const float* __restrict__ wq,
                                                const float* __restrict__ wk,
                                                const float* __restrict__ wv,
                                                unsigned short* __restrict__ xb,
                                                unsigned short* __restrict__ wb,
                                                float* __restrict__ pass) {
    const int i = (blockIdx.x * 256 + threadIdx.x) * 8;
    const float* src;
    unsigned short* dst;
    bool isx = i < MROWS * EMB;
    if (isx) {
        src = x + i;
        dst = xb + i;
    } else {
        const int j = i - MROWS * EMB;
        src = (j < NW) ? wq + j : (j < 2 * NW) ? wk + (j - NW) : wv + (j - 2 * NW);
        dst = wb + j;
    }
    const float4* s = reinterpret_cast<const float4*>(src);
    float4 f0 = s[0];
    float4 f1 = s[1];
    union { unsigned short u[8]; short8 v; } o;
    o.u[0] = f2bf(f0.x); o.u[1] = f2bf(f0.y); o.u[2] = f2bf(f0.z); o.u[3] = f2bf(f0.w);
    o.u[4] = f2bf(f1.x); o.u[5] = f2bf(f1.y); o.u[6] = f2bf(f1.z); o.u[7] = f2bf(f1.w);
    *reinterpret_cast<short8*>(dst) = o.v;
    if (isx) {
        float4* p = reinterpret_cast<float4*>(pass + i);
        p[0] = f0;
        p[1] = f1;
    }
}

// ---------------- 8-wave 256-wide pipelined GEMM ------------------------
// C[m,n] = sum_k A[m,k] * B[n,k]  (NT, bf16 in), K = 1024, BK = 32.
// 3 LDS buffers, depth-2 prefetch via global_load_lds, one raw s_barrier +
// counted vmcnt per K-tile (T3+T4), setprio on MFMA (T5), granule swizzle
// via pre-swizzled global source (T2, rule #21).
// MODE 0: BN=256, cols span [Wq|Wk]; bf16 head-major out, Q scaled QSCALE.
// MODE 1: BN=128, f32 out scaled by num/(pp0+pp1) (softmax-diag combine).
template <int MODE>
__global__ __launch_bounds__(512, 2) void gemm8(const short* __restrict__ A,
                                                const short* __restrict__ Bm,
                                                unsigned short* __restrict__ Cb,
                                                float* __restrict__ out,
                                                const float* __restrict__ num,
                                                const float* __restrict__ pp) {
    constexpr int K = EMB;
    constexpr int NT = K / 32;                 // 32 K-tiles
    constexpr int BN = (MODE == 0) ? 256 : 128;
    constexpr int NF = BN / 64;                // N-frags per wave: 4 or 2
    constexpr int BUFSTRIDE = 8192 + BN * 32;  // shorts per buffer
    constexpr int VW = 2 + BN / 128;           // vmem ops per wave per tile: 4 or 3

    __shared__ short Ks[3 * BUFSTRIDE];        // 96 KB (MODE0) / 72 KB (MODE1)

    const int t = threadIdx.x;
    const int lane = t & 63;
    const int w = t >> 6;            // 0..7
    const int wr = w >> 2;           // 0..1   M half
    const int wc = w & 3;            // 0..3   N quarter
    const int rl = lane & 15;
    const int pg = (lane >> 4) ^ (lane & 3);   // swizzled read granule
    const int m0 = blockIdx.x * 256;
    const int n0 = blockIdx.y * BN;

    const int sr = t >> 2;                     // 0..127
    const int sg = (t & 3) ^ (sr & 3);
    const int soff = sr * K + sg * 8;
    const short* gA0 = A + (size_t)(m0)*K + soff;
    const short* gA1 = A + (size_t)(m0 + 128) * K + soff;
    const short* gB0 = Bm + (size_t)(n0)*K + soff;
    const short* gB1 = Bm + (size_t)(n0 + 128) * K + soff;  // MODE0 only
    short* ldsw = Ks + w * 512;                // wave-uniform stage base

#define STAGE8(kk, bb)                                               \
    {                                                                \
        const int _k = (kk)*32;                                      \
        short* _l = ldsw + (bb)*BUFSTRIDE;                           \
        gl_lds16(gA0 + _k, _l);                                      \
        gl_lds16(gA1 + _k, _l + 4096);                               \
        gl_lds16(gB0 + _k, _l + 8192);                               \
        if (MODE == 0) gl_lds16(gB1 + _k, _l + 12288);               \
    }

    f32x4 acc[8][NF] = {};

    // prologue: tiles 0,1 -> bufs 0,1
    STAGE8(0, 0);
    STAGE8(1, 1);
    waitvm<VW>();                    // tile 0 landed
    __builtin_amdgcn_s_barrier();

    int cur = 0;
    for (int kt = 0; kt < NT; ++kt) {
        const int pf = kt + 2;
        if (pf < NT) {
            int nb = cur + 2; if (nb >= 3) nb -= 3;
            STAGE8(pf, nb);
        }

        const short* bufp = Ks + cur * BUFSTRIDE;
        short8 av[8], bv[NF];
#pragma unroll
        for (int i = 0; i < 8; i++)
            av[i] = *(const short8*)&bufp[wr * 4096 + i * 512 + rl * 32 + pg * 8];
#pragma unroll
        for (int j = 0; j < NF; j++) {
            const int brow = (MODE == 0) ? ((wc & 1) * 64 + j * 16 + rl)
                                         : (wc * 32 + j * 16 + rl);
            const int bh = (MODE == 0) ? (wc >> 1) : 0;
            bv[j] = *(const short8*)&bufp[8192 + bh * 4096 + brow * 32 + pg * 8];
        }

        __builtin_amdgcn_s_setprio(1);
#pragma unroll
        for (int i = 0; i < 8; i++)
#pragma unroll
            for (int j = 0; j < NF; j++)
                acc[i][j] = __builtin_amdgcn_mfma_f32_16x16x32_bf16(av[i], bv[j], acc[i][j], 0, 0, 0);
        __builtin_amdgcn_s_setprio(0);

        if (kt < NT - 2) waitvm<VW>();   // next tile landed; prefetch stays in flight
        else             waitvm<0>();
        __builtin_amdgcn_s_barrier();

        cur += 1; if (cur == 3) cur = 0;
    }
#undef STAGE8

    // epilogue: C layout col = lane&15, row = 4*(lane>>4)+r
    const int gr_base = m0 + wr * 128 + (lane >> 4) * 4;
    const int gc_base = n0 + wc * (BN / 4) + rl;
#pragma unroll
    for (int i = 0; i < 8; i++) {
#pragma unroll
        for (int j = 0; j < NF; j++) {
            const int col = gc_base + j * 16;
#pragma unroll
            for (int r = 0; r < 4; r++) {
                const int grow = gr_base + i * 16 + r;
                const int bb = grow >> 11;
                const int nn = grow & 2047;
                if (MODE == 0) {
                    const int sel = col >> 10;       // 0 = Q, 1 = K
                    const int cc = col & 1023;
                    const int hh = cc >> 6;
                    const int dd = cc & 63;
                    const float sc = sel ? 1.0f : QSCALE;
                    Cb[(((size_t)((sel << 6) + (bb << 4) + hh) * SEQ + nn) << 6) + dd] =
                        f2bf(acc[i][j][r] * sc);
                } else {
                    const int hh = col >> 6;
                    const int idx = ((bb << 4) + hh) * SEQ + nn;
                    const float d = num[idx] / (pp[idx] + pp[idx + 64 * SEQ]);
                    out[(size_t)grow * EMB + col] = acc[i][j][r] * d;
                }
            }
        }
    }
}

// ---------------- diag kernel v14: 64 q-rows/wave, 256 thr, no reg cap ---
// Qh/Kh head-major [64][2048][64] bf16 (Q pre-scaled by QSCALE).
// Block = (bh, qt: 256 q-rows, ks: k half). 256 thr = 4 waves x 64 q-rows
// (4 q-tiles) -> one LDS read pair feeds 8 MFMAs (LDS reads/score halved
// vs the 46.5us best). launch_bounds(256,2): no artificial 64-VGPR cap
// (r14 lesson: (512,4) caps at 64 and spills). Grid 1024 = 4 blocks/CU =
// 16 waves/CU. Block-cooperative gl_lds staging (pre-swizzled global src,
// rule #21; same phys=logical^(row&7) invariant as v7/v8), 3 LDS bufs,
// depth-2 prefetch, counted vmcnt(4), ONE barrier/tile, no setprio.
// Writes partials pp[ks][bh][q]; ks==0 blocks also write num[bh][q].
__global__ __launch_bounds__(256, 2) void diag_kernel(const short* __restrict__ Qh,
                                                      const short* __restrict__ Kh,
                                                      float* __restrict__ num,
                                                      float* __restrict__ pp) {
    const int n = blockIdx.x;
    const int bh = (n & 7) | ((n >> 7) << 3);   // 0..63 (v8 XCD-pinned map)
    const int qt = (n >> 3) & 7;                // 8 q-tiles of 256 rows
    const int ks = (n >> 6) & 1;                // k half (1024 rows)
    __shared__ short Ksd[3 * 8192];             // 3 bufs x 128 rows x 64

    const int t = threadIdx.x;
    const int lane = t & 63;
    const int w = t >> 6;               // 0..3
    const int rl = lane & 15;
    const int g = lane >> 4;            // 0..3
    const int kq = g * 8;

    const short* Kbh = Kh + (size_t)bh * SEQ * DHEAD;
    const short* Qbh = Qh + (size_t)bh * SEQ * DHEAD;

    // Q fragments: 4 tiles of 16 rows (64 q-rows per wave)
    const int qbase = qt * 256 + w * 64;
    short8 a0[4], a1[4];
#pragma unroll
    for (int i = 0; i < 4; i++) {
        const int qrow = qbase + i * 16 + rl;
        a0[i] = *(const short8*)(Qbh + qrow * DHEAD + kq);
        a1[i] = *(const short8*)(Qbh + qrow * DHEAD + kq + 32);
    }

    const int rr = rl - g * 4;          // valid lane iff 0 <= rr < 4

    // diag numerator pre-pass: ks==0 blocks only (global K reads, cheap)
    if (ks == 0) {
        float sdiag[4];
#pragma unroll
        for (int i = 0; i < 4; i++) {
            const int krow = qbase + i * 16 + rl;
            const short8 b0d = *(const short8*)(Kbh + krow * DHEAD + kq);
            const short8 b1d = *(const short8*)(Kbh + krow * DHEAD + kq + 32);
            f32x4 cd = {};
            cd = __builtin_amdgcn_mfma_f32_16x16x32_bf16(a0[i], b0d, cd, 0, 0, 0);
            cd = __builtin_amdgcn_mfma_f32_16x16x32_bf16(a1[i], b1d, cd, 0, 0, 0);
            sdiag[i] = (rr >= 0 && rr < 4) ? cd[rr] : 0.f;
        }
        if (rr >= 0 && rr < 4) {
#pragma unroll
            for (int i = 0; i < 4; i++)
                num[bh * SEQ + qbase + i * 16 + rl] =
                    __builtin_amdgcn_exp2f(sdiag[i]);
        }
    }

    // staging: 256 thr x 4 gl_lds cover a 128x64 tile. Wave w inst i writes
    // LDS granules [(i*4+w)*64 .. +64); lane's granule G=(i*4+w)*64+lane ->
    // LDS (row=G>>3, col=G&7). Source pre-swizzled: col' = col ^ (row&7),
    // where row = (i*4+w)*8 + (lane>>3), so row&7 = lane>>3.
    const int srow_l = lane >> 3;               // 0..7
    const int scol = ((lane & 7) ^ srow_l) * 8; // pre-swizzled source col
    const short* gKb = Kbh + (size_t)ks * 1024 * DHEAD;
    const short* gK0 = gKb + ((0 * 4 + w) * 8 + srow_l) * DHEAD + scol;
    const short* gK1 = gKb + ((1 * 4 + w) * 8 + srow_l) * DHEAD + scol;
    const short* gK2 = gKb + ((2 * 4 + w) * 8 + srow_l) * DHEAD + scol;
    const short* gK3 = gKb + ((3 * 4 + w) * 8 + srow_l) * DHEAD + scol;
    short* ldsw = Ksd + w * 512;                // wave-uniform stage base

#define DSTAGE(kk, bb)                                        \
    {                                                         \
        short* _l = ldsw + (bb)*8192;                         \
        gl_lds16(gK0 + (kk)*8192, _l);                        \
        gl_lds16(gK1 + (kk)*8192, _l + 2048);                 \
        gl_lds16(gK2 + (kk)*8192, _l + 4096);                 \
        gl_lds16(gK3 + (kk)*8192, _l + 6144);                 \
    }

    // swizzled read blocks (row&7 == rl&7 since rows step by 16)
    const int blk0 = (g ^ (rl & 7)) * 8;
    const int blk1 = ((g + 4) ^ (rl & 7)) * 8;

    float ssum[4][4] = {};

    waitvm<0>();                        // drain pre-pass loads for exact counts
    DSTAGE(0, 0);
    DSTAGE(1, 1);
    waitvm<4>();                        // tile 0 landed
    __builtin_amdgcn_s_barrier();

    int cur = 0;
    for (int kt = 0; kt < 8; ++kt) {
        if (kt + 2 < 8) {
            int nb = cur + 2; if (nb >= 3) nb -= 3;
            DSTAGE(kt + 2, nb);
        }
        const short* bufp = Ksd + cur * 8192;

#pragma unroll
        for (int sub = 0; sub < 8; ++sub) {
            const short* rp = bufp + (sub * 16 + rl) * 64;
            const short8 b0 = *(const short8*)(rp + blk0);
            const short8 b1 = *(const short8*)(rp + blk1);
            f32x4 c[4];
#pragma unroll
            for (int i = 0; i < 4; i++) {
                c[i] = __builtin_amdgcn_mfma_f32_16x16x32_bf16(a0[i], b0, f32x4{}, 0, 0, 0);
                c[i] = __builtin_amdgcn_mfma_f32_16x16x32_bf16(a1[i], b1, c[i], 0, 0, 0);
            }
#pragma unroll
            for (int i = 0; i < 4; i++)
#pragma unroll
                for (int r = 0; r < 4; ++r)
                    ssum[i][r] += __builtin_amdgcn_exp2f(c[i][r]);
        }

        if (kt < 7) {
            if (kt < 6) waitvm<4>();
            else        waitvm<0>();
            __builtin_amdgcn_s_barrier();
        }
        cur += 1; if (cur == 3) cur = 0;
    }
#undef DSTAGE

    // reduce partial sums across the 16-lane column groups
#pragma unroll
    for (int i = 0; i < 4; i++)
#pragma unroll
        for (int r = 0; r < 4; r++) {
            float v = ssum[i][r];
            v += __shfl_xor(v, 1);
            v += __shfl_xor(v, 2);
            v += __shfl_xor(v, 4);
            v += __shfl_xor(v, 8);
            ssum[i][r] = v;
        }

    if (rr >= 0 && rr < 4) {
#pragma unroll
        for (int i = 0; i < 4; i++)
            pp[(ks * 64 + bh) * SEQ + qbase + i * 16 + rl] = ssum[i][rr];
    }
}

extern "C" void kernel_launch(void* const* d_in, const int* in_sizes, int n_in,
                              void* d_out, int out_size, void* d_ws, size_t ws_size,
                              hipStream_t stream) {
    const float* x  = (const float*)d_in[0];
    const float* Wq = (const float*)d_in[1];
    const float* Wk = (const float*)d_in[2];
    const float* Wv = (const float*)d_in[3];
    float* out = (float*)d_out;
    char* ws = (char*)d_ws;

    const size_t xb_off  = 0;
    const size_t wq_off  = xb_off + (size_t)MROWS * EMB * 2;
    const size_t wk_off  = wq_off + (size_t)NW * 2;          // contiguous after wq
    const size_t wv_off  = wk_off + (size_t)NW * 2;
    const size_t q_off   = wv_off + (size_t)NW * 2;
    const size_t k_off   = q_off + (size_t)MROWS * EMB * 2;  // contiguous after q
    const size_t num_off = k_off + (size_t)MROWS * EMB * 2;
    const size_t pp_off  = num_off + (size_t)64 * SEQ * 4;

    short* xb  = (short*)(ws + xb_off);
    short* wqb = (short*)(ws + wq_off);
    short* wvb = (short*)(ws + wv_off);
    short* Qh  = (short*)(ws + q_off);
    short* Kh  = (short*)(ws + k_off);
    float* num = (float*)(ws + num_off);
    float* pp  = (float*)(ws + pp_off);

    const int npack = (MROWS * EMB + 3 * NW) / 2048;   // 5632 blocks

    pack_all<<<npack, 256, 0, stream>>>(x, Wq, Wk, Wv,
                                        (unsigned short*)xb, (unsigned short*)wqb,
                                        out + (size_t)MROWS * EMB);

    // fused Q+K projection: B = [Wq | Wk] (contiguous), N = 2048
    gemm8<0><<<dim3(MROWS / 256, 2048 / 256), 512, 0, stream>>>(
        xb, wqb, (unsigned short*)Qh, nullptr, nullptr, nullptr);

    diag_kernel<<<1024, 256, 0, stream>>>(Qh, Kh, num, pp);

    gemm8<1><<<dim3(MROWS / 256, EMB / 128), 512, 0, stream>>>(
        xb, wvb, nullptr, out, num, pp);
}

// Round 16
// 130.757 us; speedup vs baseline: 2.6746x; 1.0206x over previous
//
#include <hip/hip_runtime.h>
#include <hip/hip_bf16.h>
#include <stdint.h>

typedef __attribute__((ext_vector_type(8))) short short8;
typedef __attribute__((ext_vector_type(4))) float f32x4;

// Problem constants
#define BATCH 4
#define SEQ   2048
#define EMB   1024
#define HEADS 16
#define DHEAD 64
#define MROWS (BATCH * SEQ)   // 8192
#define NW    (EMB * EMB)     // 1048576

// exp(s/8) == exp2(s * 0.125*log2(e)); fold into Q at bf16-pack time
#define QSCALE 0.18033688011112042f

__device__ inline unsigned short f2bf(float f) {
    unsigned int u = __float_as_uint(f);
    unsigned int r = (u + 0x7fffu + ((u >> 16) & 1u)) >> 16;
    return (unsigned short)r;
}

__device__ __forceinline__ void gl_lds16(const short* g, short* l) {
    __builtin_amdgcn_global_load_lds(
        (const __attribute__((address_space(1))) void*)g,
        (__attribute__((address_space(3))) void*)l, 16, 0, 0);
}

template <int N>
__device__ __forceinline__ void waitvm() {
    asm volatile("s_waitcnt vmcnt(%0)" :: "n"(N) : "memory");
}

// ------- fused pack: x -> bf16 + f32 passthrough, and Wq|Wk|Wv -> bf16 ---
__global__ __launch_bounds__(256) void pack_all(const float* __restrict__ x,
                                                const float* __restrict__ wq,
                                                const float* __restrict__ wk,
                                                const float* __restrict__ wv,
                                                unsigned short* __restrict__ xb,
                                                unsigned short* __restrict__ wb,
                                                float* __restrict__ pass) {
    const int i = (blockIdx.x * 256 + threadIdx.x) * 8;
    const float* src;
    unsigned short* dst;
    bool isx = i < MROWS * EMB;
    if (isx) {
        src = x + i;
        dst = xb + i;
    } else {
        const int j = i - MROWS * EMB;
        src = (j < NW) ? wq + j : (j < 2 * NW) ? wk + (j - NW) : wv + (j - 2 * NW);
        dst = wb + j;
    }
    const float4* s = reinterpret_cast<const float4*>(src);
    float4 f0 = s[0];
    float4 f1 = s[1];
    union { unsigned short u[8]; short8 v; } o;
    o.u[0] = f2bf(f0.x); o.u[1] = f2bf(f0.y); o.u[2] = f2bf(f0.z); o.u[3] = f2bf(f0.w);
    o.u[4] = f2bf(f1.x); o.u[5] = f2bf(f1.y); o.u[6] = f2bf(f1.z); o.u[7] = f2bf(f1.w);
    *reinterpret_cast<short8*>(dst) = o.v;
    if (isx) {
        float4* p = reinterpret_cast<float4*>(pass + i);
        p[0] = f0;
        p[1] = f1;
    }
}

// ---------------- 8-wave 256-wide pipelined GEMM ------------------------
// C[m,n] = sum_k A[m,k] * B[n,k]  (NT, bf16 in), K = 1024, BK = 32.
// 3 LDS buffers, depth-2 prefetch via global_load_lds, one raw s_barrier +
// counted vmcnt per K-tile (T3+T4), setprio on MFMA (T5), granule swizzle
// via pre-swizzled global source (T2, rule #21).
// MODE 0: BN=256, cols span [Wq|Wk]; bf16 head-major out, Q scaled QSCALE.
// MODE 1: BN=128, f32 out scaled by num/(pp0+pp1) (softmax-diag combine).
template <int MODE>
__global__ __launch_bounds__(512, 2) void gemm8(const short* __restrict__ A,
                                                const short* __restrict__ Bm,
                                                unsigned short* __restrict__ Cb,
                                                float* __restrict__ out,
                                                const float* __restrict__ num,
                                                const float* __restrict__ pp) {
    constexpr int K = EMB;
    constexpr int NT = K / 32;                 // 32 K-tiles
    constexpr int BN = (MODE == 0) ? 256 : 128;
    constexpr int NF = BN / 64;                // N-frags per wave: 4 or 2
    constexpr int BUFSTRIDE = 8192 + BN * 32;  // shorts per buffer
    constexpr int VW = 2 + BN / 128;           // vmem ops per wave per tile: 4 or 3

    __shared__ short Ks[3 * BUFSTRIDE];        // 96 KB (MODE0) / 72 KB (MODE1)

    const int t = threadIdx.x;
    const int lane = t & 63;
    const int w = t >> 6;            // 0..7
    const int wr = w >> 2;           // 0..1   M half
    const int wc = w & 3;            // 0..3   N quarter
    const int rl = lane & 15;
    const int pg = (lane >> 4) ^ (lane & 3);   // swizzled read granule
    const int m0 = blockIdx.x * 256;
    const int n0 = blockIdx.y * BN;

    const int sr = t >> 2;                     // 0..127
    const int sg = (t & 3) ^ (sr & 3);
    const int soff = sr * K + sg * 8;
    const short* gA0 = A + (size_t)(m0)*K + soff;
    const short* gA1 = A + (size_t)(m0 + 128) * K + soff;
    const short* gB0 = Bm + (size_t)(n0)*K + soff;
    const short* gB1 = Bm + (size_t)(n0 + 128) * K + soff;  // MODE0 only
    short* ldsw = Ks + w * 512;                // wave-uniform stage base

#define STAGE8(kk, bb)                                               \
    {                                                                \
        const int _k = (kk)*32;                                      \
        short* _l = ldsw + (bb)*BUFSTRIDE;                           \
        gl_lds16(gA0 + _k, _l);                                      \
        gl_lds16(gA1 + _k, _l + 4096);                               \
        gl_lds16(gB0 + _k, _l + 8192);                               \
        if (MODE == 0) gl_lds16(gB1 + _k, _l + 12288);               \
    }

    f32x4 acc[8][NF] = {};

    // prologue: tiles 0,1 -> bufs 0,1
    STAGE8(0, 0);
    STAGE8(1, 1);
    waitvm<VW>();                    // tile 0 landed
    __builtin_amdgcn_s_barrier();

    int cur = 0;
    for (int kt = 0; kt < NT; ++kt) {
        const int pf = kt + 2;
        if (pf < NT) {
            int nb = cur + 2; if (nb >= 3) nb -= 3;
            STAGE8(pf, nb);
        }

        const short* bufp = Ks + cur * BUFSTRIDE;
        short8 av[8], bv[NF];
#pragma unroll
        for (int i = 0; i < 8; i++)
            av[i] = *(const short8*)&bufp[wr * 4096 + i * 512 + rl * 32 + pg * 8];
#pragma unroll
        for (int j = 0; j < NF; j++) {
            const int brow = (MODE == 0) ? ((wc & 1) * 64 + j * 16 + rl)
                                         : (wc * 32 + j * 16 + rl);
            const int bh = (MODE == 0) ? (wc >> 1) : 0;
            bv[j] = *(const short8*)&bufp[8192 + bh * 4096 + brow * 32 + pg * 8];
        }

        __builtin_amdgcn_s_setprio(1);
#pragma unroll
        for (int i = 0; i < 8; i++)
#pragma unroll
            for (int j = 0; j < NF; j++)
                acc[i][j] = __builtin_amdgcn_mfma_f32_16x16x32_bf16(av[i], bv[j], acc[i][j], 0, 0, 0);
        __builtin_amdgcn_s_setprio(0);

        if (kt < NT - 2) waitvm<VW>();   // next tile landed; prefetch stays in flight
        else             waitvm<0>();
        __builtin_amdgcn_s_barrier();

        cur += 1; if (cur == 3) cur = 0;
    }
#undef STAGE8

    // epilogue: C layout col = lane&15, row = 4*(lane>>4)+r
    const int gr_base = m0 + wr * 128 + (lane >> 4) * 4;
    const int gc_base = n0 + wc * (BN / 4) + rl;
#pragma unroll
    for (int i = 0; i < 8; i++) {
#pragma unroll
        for (int j = 0; j < NF; j++) {
            const int col = gc_base + j * 16;
#pragma unroll
            for (int r = 0; r < 4; r++) {
                const int grow = gr_base + i * 16 + r;
                const int bb = grow >> 11;
                const int nn = grow & 2047;
                if (MODE == 0) {
                    const int sel = col >> 10;       // 0 = Q, 1 = K
                    const int cc = col & 1023;
                    const int hh = cc >> 6;
                    const int dd = cc & 63;
                    const float sc = sel ? 1.0f : QSCALE;
                    Cb[(((size_t)((sel << 6) + (bb << 4) + hh) * SEQ + nn) << 6) + dd] =
                        f2bf(acc[i][j][r] * sc);
                } else {
                    const int hh = col >> 6;
                    const int idx = ((bb << 4) + hh) * SEQ + nn;
                    const float d = num[idx] / (pp[idx] + pp[idx + 64 * SEQ]);
                    out[(size_t)grow * EMB + col] = acc[i][j][r] * d;
                }
            }
        }
    }
}

// ---------------- diag kernel v15 (= r8 v8 + Schraudolph exp2) -----------
// Qh/Kh head-major [64][2048][64] bf16 (Q pre-scaled by QSCALE).
// Block = (bh, qt: 256 q-rows, ks: k half). 512 thr = 8 waves x 32 q-rows.
// Grid 1024 (4 blocks/CU), 2 LDS bufs, stage-before-compute, one
// vmcnt(0)+barrier per tile. Denominator exp2 via Schraudolph bit-trick
// (fma+cvt on VALU, trans pipe freed; rel err +-3.6%/term, ~0 mean).
// Numerator keeps exact exp2. Partials pp[ks][bh][q]; ks==0 writes num.
__global__ __launch_bounds__(512, 4) void diag_kernel(const short* __restrict__ Qh,
                                                      const short* __restrict__ Kh,
                                                      float* __restrict__ num,
                                                      float* __restrict__ pp) {
    const int n = blockIdx.x;
    const int bh = (n & 7) | ((n >> 7) << 3);   // 0..63
    const int qt = (n >> 3) & 7;                // 8 q-tiles of 256 rows
    const int ks = (n >> 6) & 1;                // k half
    __shared__ short Ksd[2 * 8192];             // 2 bufs x 128 rows x 128B

    const int t = threadIdx.x;
    const int lane = t & 63;
    const int w = t >> 6;               // 0..7
    const int rl = lane & 15;
    const int g = lane >> 4;            // 0..3
    const int kq = g * 8;

    const short* Kbh = Kh + (size_t)bh * SEQ * DHEAD;
    const short* Qbh = Qh + (size_t)bh * SEQ * DHEAD;

    // Q fragments: 2 tiles of 16 rows (32 q-rows per wave)
    const int qbase = qt * 256 + w * 32;
    short8 a0[2], a1[2];
#pragma unroll
    for (int i = 0; i < 2; i++) {
        const int qrow = qbase + i * 16 + rl;
        a0[i] = *(const short8*)(Qbh + qrow * DHEAD + kq);
        a1[i] = *(const short8*)(Qbh + qrow * DHEAD + kq + 32);
    }

    // diag numerator pre-pass (global K reads; identical in both ks blocks)
    float sdiag[2];
    const int rr = rl - g * 4;          // valid lane iff 0 <= rr < 4
#pragma unroll
    for (int i = 0; i < 2; i++) {
        const int krow = qbase + i * 16 + rl;
        const short8 b0d = *(const short8*)(Kbh + krow * DHEAD + kq);
        const short8 b1d = *(const short8*)(Kbh + krow * DHEAD + kq + 32);
        f32x4 cd = {};
        cd = __builtin_amdgcn_mfma_f32_16x16x32_bf16(a0[i], b0d, cd, 0, 0, 0);
        cd = __builtin_amdgcn_mfma_f32_16x16x32_bf16(a1[i], b1d, cd, 0, 0, 0);
        sdiag[i] = (rr >= 0 && rr < 4) ? cd[rr] : 0.f;
    }

    // staging: thread t sources granule (row t>>3, block (t&7)^(row&7));
    // LDS dest linear => LDS holds logical block b at b^(row&7) (rule #21).
    const int sr = t >> 3;              // 0..63
    const int sb = ((t & 7) ^ (sr & 7)) * 8;
    const short* gK0 = Kbh + (size_t)ks * (SEQ / 2) * DHEAD + sr * DHEAD + sb;
    const short* gK1 = gK0 + 64 * DHEAD;
    short* ldsw = Ksd + w * 512;        // wave-uniform stage base

#define DSTAGE(kk, bb)                                       \
    {                                                        \
        gl_lds16(gK0 + (kk)*8192, ldsw + (bb)*8192);         \
        gl_lds16(gK1 + (kk)*8192, ldsw + (bb)*8192 + 4096);  \
    }

    // swizzled read blocks (row&7 == lane&7 since rows step by 16)
    const int blk0 = (g ^ (lane & 7)) * 8;
    const int blk1 = ((g + 4) ^ (lane & 7)) * 8;

    float ssum[2][4] = {};

    DSTAGE(0, 0);
    waitvm<0>();
    __builtin_amdgcn_s_barrier();

#define QKMFMA(sub, c)                                                          \
    {                                                                           \
        const short* _r = bufp + ((sub)*16 + rl) * 64;                          \
        const short8 _b0 = *(const short8*)(_r + blk0);                         \
        const short8 _b1 = *(const short8*)(_r + blk1);                         \
        c[0] = __builtin_amdgcn_mfma_f32_16x16x32_bf16(a0[0], _b0, f32x4{}, 0, 0, 0); \
        c[0] = __builtin_amdgcn_mfma_f32_16x16x32_bf16(a1[0], _b1, c[0], 0, 0, 0);    \
        c[1] = __builtin_amdgcn_mfma_f32_16x16x32_bf16(a0[1], _b0, f32x4{}, 0, 0, 0); \
        c[1] = __builtin_amdgcn_mfma_f32_16x16x32_bf16(a1[1], _b1, c[1], 0, 0, 0);    \
    }
// Schraudolph: 2^x ~= int_as_float((int)(x*2^23 + (127<<23 - 294486)))
// 2 VALU ops, no trans; balanced rel err +-3.6%, ~zero-mean over a sum.
#define EXPACC(c)                                                       \
    {                                                                   \
        _Pragma("unroll") for (int i = 0; i < 2; i++)                   \
        _Pragma("unroll") for (int r = 0; r < 4; ++r) {                 \
            const float _t = fmaf(c[i][r], 8388608.0f, 1065058730.0f);  \
            ssum[i][r] += __int_as_float((int)_t);                      \
        }                                                               \
    }

    for (int kt = 0; kt < 8; ++kt) {
        if (kt < 7) DSTAGE(kt + 1, (kt + 1) & 1);
        const short* bufp = Ksd + (kt & 1) * 8192;

        f32x4 cE[2], cO[2];
        QKMFMA(0, cE);
        QKMFMA(1, cO);
        EXPACC(cE);
        QKMFMA(2, cE);
        EXPACC(cO);
        QKMFMA(3, cO);
        EXPACC(cE);
        QKMFMA(4, cE);
        EXPACC(cO);
        QKMFMA(5, cO);
        EXPACC(cE);
        QKMFMA(6, cE);
        EXPACC(cO);
        QKMFMA(7, cO);
        EXPACC(cE);
        EXPACC(cO);

        if (kt < 7) {
            waitvm<0>();
            __builtin_amdgcn_s_barrier();
        }
    }
#undef DSTAGE
#undef QKMFMA
#undef EXPACC

    // reduce partial sums across the 16-lane column groups
#pragma unroll
    for (int i = 0; i < 2; i++)
#pragma unroll
        for (int r = 0; r < 4; r++) {
            float v = ssum[i][r];
            v += __shfl_xor(v, 1);
            v += __shfl_xor(v, 2);
            v += __shfl_xor(v, 4);
            v += __shfl_xor(v, 8);
            ssum[i][r] = v;
        }

    if (rr >= 0 && rr < 4) {
#pragma unroll
        for (int i = 0; i < 2; i++) {
            const int q = qbase + i * 16 + rl;
            pp[(ks * 64 + bh) * SEQ + q] = ssum[i][rr];
            if (ks == 0) num[bh * SEQ + q] = __builtin_amdgcn_exp2f(sdiag[i]);
        }
    }
}

extern "C" void kernel_launch(void* const* d_in, const int* in_sizes, int n_in,
                              void* d_out, int out_size, void* d_ws, size_t ws_size,
                              hipStream_t stream) {
    const float* x  = (const float*)d_in[0];
    const float* Wq = (const float*)d_in[1];
    const float* Wk = (const float*)d_in[2];
    const float* Wv = (const float*)d_in[3];
    float* out = (float*)d_out;
    char* ws = (char*)d_ws;

    const size_t xb_off  = 0;
    const size_t wq_off  = xb_off + (size_t)MROWS * EMB * 2;
    const size_t wk_off  = wq_off + (size_t)NW * 2;          // contiguous after wq
    const size_t wv_off  = wk_off + (size_t)NW * 2;
    const size_t q_off   = wv_off + (size_t)NW * 2;
    const size_t k_off   = q_off + (size_t)MROWS * EMB * 2;  // contiguous after q
    const size_t num_off = k_off + (size_t)MROWS * EMB * 2;
    const size_t pp_off  = num_off + (size_t)64 * SEQ * 4;

    short* xb  = (short*)(ws + xb_off);
    short* wqb = (short*)(ws + wq_off);
    short* wvb = (short*)(ws + wv_off);
    short* Qh  = (short*)(ws + q_off);
    short* Kh  = (short*)(ws + k_off);
    float* num = (float*)(ws + num_off);
    float* pp  = (float*)(ws + pp_off);

    const int npack = (MROWS * EMB + 3 * NW) / 2048;   // 5632 blocks

    pack_all<<<npack, 256, 0, stream>>>(x, Wq, Wk, Wv,
                                        (unsigned short*)xb, (unsigned short*)wqb,
                                        out + (size_t)MROWS * EMB);

    // fused Q+K projection: B = [Wq | Wk] (contiguous), N = 2048
    gemm8<0><<<dim3(MROWS / 256, 2048 / 256), 512, 0, stream>>>(
        xb, wqb, (unsigned short*)Qh, nullptr, nullptr, nullptr);

    diag_kernel<<<1024, 512, 0, stream>>>(Qh, Kh, num, pp);

    gemm8<1><<<dim3(MROWS / 256, EMB / 128), 512, 0, stream>>>(
        xb, wvb, nullptr, out, num, pp);
}